// Round 4
// baseline (688.231 us; speedup 1.0000x reference)
//
#include <hip/hip_runtime.h>
#include <hip/hip_fp16.h>
#include <cstdint>
#include <cstddef>

// Problem constants (fixed by the reference)
static constexpr int NN = 100000;   // nodes
static constexpr int NE = 3200000;  // edges
static constexpr int NG = 256;      // graphs
static constexpr int NBK = (NN + 127) / 128;  // dst buckets of 128 nodes = 782
static constexpr int EPB = NE / 256;          // edges per hist/scatter block = 12500
static constexpr int GB_BATCH = (NN + 255) / 256;                    // 391
static constexpr int GB_PREPW = (192 * 128 + 192 * 64 + 255) / 256;  // 144
static constexpr int GB_HIST = 256;

typedef _Float16 h8 __attribute__((ext_vector_type(8)));
typedef float f4v __attribute__((ext_vector_type(4)));

__device__ __forceinline__ void atomAddF(float* p, float v) {
  unsafeAtomicAdd(p, v);  // native global_atomic_add_f32 on gfx950
}
__device__ __forceinline__ float h2f(__half h) { return __half2float(h); }

// ---------------------------------------------------------------------------
// dtype hedge: reference says int64, harness doc says int32. Detect at runtime.
__global__ void k_detect(const int* __restrict__ ei, int* __restrict__ flag) {
  if (threadIdx.x == 0 && blockIdx.x == 0) {
    int nz = 0;
    for (int i = 0; i < 64; ++i) nz += (ei[2 * i + 1] != 0) ? 1 : 0;
    *flag = (nz == 0) ? 1 : 0;  // 1 => int64 layout
  }
}

__device__ __forceinline__ int ld_idx(const void* raw, int f, int i) {
  return f ? (int)((const long long*)raw)[i] : ((const int*)raw)[i];
}

// ---------------------------------------------------------------------------
// Front kernel: blockIdx ranges -> [batch repack+gcnt | weight prep | edge hist]
// Src-side: out-degree via direct global atomics (srclist machinery removed —
// its only consumer was the degree count; the random 4B scatter writes it
// required were cache-line ping-pong between CUs).
__global__ __launch_bounds__(256) void k_front(const void* __restrict__ bat,
                                               const void* __restrict__ ei,
                                               const int* __restrict__ flag,
                                               const float* __restrict__ W1,
                                               const float* __restrict__ W2,
                                               int* __restrict__ b32,
                                               int* __restrict__ gcnt,
                                               __half* __restrict__ BtX,
                                               __half* __restrict__ BtH2,
                                               int* __restrict__ deg,
                                               int* __restrict__ dCnt,
                                               int* __restrict__ hdBlk) {
  __shared__ int sh[NBK];
  int b = blockIdx.x;
  int t = threadIdx.x;
  if (b < GB_BATCH) {
    int* cnt = sh;
    cnt[t] = 0;
    int blk0 = b * 256;
    int f = *flag;
    int g0 = ld_idx(bat, f, blk0);
    __syncthreads();
    int i = blk0 + t;
    if (i < NN) {
      int g = ld_idx(bat, f, i);
      b32[i] = g;
      atomicAdd(&cnt[g - g0], 1);
    }
    __syncthreads();
    if (cnt[t] > 0) atomicAdd(&gcnt[g0 + t], cnt[t]);
  } else if (b < GB_BATCH + GB_PREPW) {
    // BtX[192][128]: rows 0-63=(W1_0-W1_2)^T, 64-127=W1_1^T, 128-191=W1_2^T
    // BtH2[192][64]: rows 0-63=(W2_0-W2_2)^T, 64-127=W2_1^T, 128-191=W2_2^T
    int u = (b - GB_BATCH) * 256 + t;
    if (u < 192 * 128) {
      int n = u >> 7, k = u & 127;
      float v;
      if (n < 64)       v = W1[k * 64 + n] - W1[16384 + k * 64 + n];
      else if (n < 128) v = W1[8192 + k * 64 + (n - 64)];
      else              v = W1[16384 + k * 64 + (n - 128)];
      BtX[n * 128 + k] = __float2half_rn(v);
    } else if (u < 192 * 128 + 192 * 64) {
      int u2 = u - 192 * 128;
      int n = u2 >> 6, k = u2 & 63;
      float v;
      if (n < 64)       v = W2[k * 64 + n] - W2[8192 + k * 64 + n];
      else if (n < 128) v = W2[4096 + k * 64 + (n - 64)];
      else              v = W2[8192 + k * 64 + (n - 128)];
      BtH2[n * 64 + k] = __float2half_rn(v);
    }
  } else {
    int hb = b - GB_BATCH - GB_PREPW;
    int* hd = sh;
    for (int i = t; i < NBK; i += 256) hd[i] = 0;
    __syncthreads();
    int f = *flag;
    int e0 = hb * EPB;
    for (int e = e0 + t; e < e0 + EPB; e += 256) {
      int s = ld_idx(ei, f, e);
      int d = ld_idx(ei, f, NE + e);
      atomicAdd(&deg[s], 1);        // out-degree, low contention (~32/node)
      atomicAdd(&hd[d >> 7], 1);
    }
    __syncthreads();
    size_t hoff = (size_t)hb * NBK;
    for (int i = t; i < NBK; i += 256) {
      int c = hd[i];
      hdBlk[hoff + i] = c;
      if (c) atomicAdd(&dCnt[i], c);
    }
  }
}

// dinv[i] = deg>0 ? rsqrt(deg) : 0
__global__ void k_dinv(const int* __restrict__ deg, float* __restrict__ dinv) {
  int i = blockIdx.x * 256 + threadIdx.x;
  if (i < NN) {
    int c = deg[i];
    dinv[i] = (c > 0) ? rsqrtf((float)c) : 0.f;
  }
}

// Exclusive scan of the dst bucket-count array (782 <= 1024, one block).
__global__ __launch_bounds__(1024) void k_scan(const int* __restrict__ dCnt,
                                               int* __restrict__ dBase,
                                               int* __restrict__ dCur) {
  __shared__ int sh2[1024];
  int t = threadIdx.x;
  int v2 = (t < NBK) ? dCnt[t] : 0;
  sh2[t] = v2;
  __syncthreads();
  for (int off = 1; off < 1024; off <<= 1) {
    int a2 = (t >= off) ? sh2[t - off] : 0;
    __syncthreads();
    sh2[t] += a2;
    __syncthreads();
  }
  if (t <= NBK) {
    int b2 = sh2[t] - v2;  // exclusive
    dBase[t] = b2;
    if (t < NBK) dCur[t] = b2;
  }
}

// Pass 2: chunk-reserve per (block,bucket) using saved per-block hists,
// scatter packed (src | dst_local<<17) records by dst bucket.
__global__ __launch_bounds__(256) void k_scatter(const void* __restrict__ raw,
                                                 const int* __restrict__ flag,
                                                 const int* __restrict__ hdBlk,
                                                 int* __restrict__ dCur,
                                                 unsigned* __restrict__ elist) {
  __shared__ int hd[NBK], cbD[NBK];
  int t = threadIdx.x;
  size_t hb = (size_t)blockIdx.x * NBK;
  for (int i = t; i < NBK; i += 256) {
    int c2 = hdBlk[hb + i];
    cbD[i] = c2 ? atomicAdd(&dCur[i], c2) : 0;
    hd[i] = 0;
  }
  __syncthreads();
  int f = *flag;
  int e0 = blockIdx.x * EPB;
  for (int e = e0 + t; e < e0 + EPB; e += 256) {
    int s = ld_idx(raw, f, e);
    int d = ld_idx(raw, f, NE + e);
    int bd = d >> 7;
    int ld2 = atomicAdd(&hd[bd], 1);
    elist[cbD[bd] + ld2] = (unsigned)s | ((unsigned)(d & 127) << 17);
  }
}

// Back kernel: per-bucket counting sort -> CSR.
// adj entries are PRE-SCALED row byte offsets (node_id * 128) so the gather
// kernels need only one 32-bit add per load against a uniform base pointer.
__global__ __launch_bounds__(256) void k_back(const int* __restrict__ dBase,
                                              const unsigned* __restrict__ elist,
                                              int* __restrict__ rowptr,
                                              int* __restrict__ adj) {
  __shared__ int cnt[128], sc[128], off[128], fill[128];
  int t = threadIdx.x;
  int b = blockIdx.x;
  if (t < 128) { cnt[t] = 0; fill[t] = 0; }
  __syncthreads();
  int e0 = dBase[b], e1 = dBase[b + 1];
  for (int i = e0 + t; i < e1; i += 256) atomicAdd(&cnt[elist[i] >> 17], 1);
  __syncthreads();
  if (t < 128) sc[t] = cnt[t];
  __syncthreads();
  for (int o = 1; o < 128; o <<= 1) {
    int a = (t < 128 && t >= o) ? sc[t - o] : 0;
    __syncthreads();
    if (t < 128) sc[t] += a;
    __syncthreads();
  }
  if (t < 128) {
    off[t] = sc[t] - cnt[t];  // exclusive
    int node = b * 128 + t;
    if (node < NN) rowptr[node] = e0 + off[t];
  }
  if (b == NBK - 1 && t == 0) rowptr[NN] = e1;
  __syncthreads();
  for (int i = e0 + t; i < e1; i += 256) {
    unsigned w2 = elist[i];
    int l = (int)(w2 >> 17);
    int pos = atomicAdd(&fill[l], 1);
    adj[e0 + off[l] + pos] = (int)((w2 & 0x1FFFFu) << 7);  // byte offset
  }
}

// ---------------------------------------------------------------------------
// MFMA GEMM X: [128 nodes] x [K=128] x [N=192].
// Outputs (all fp16): gV0 = x@(W1_0-W1_2), gA1 = x@W1_1, gU2s = dinv.*(x@W1_2).
static constexpr int AW = 136;  // LDS row stride (halves)
__global__ __launch_bounds__(256) void k_gemm_x(const float* __restrict__ x,
                                                const __half* __restrict__ BtX,
                                                const float* __restrict__ dinv,
                                                __half* __restrict__ gV0,
                                                __half* __restrict__ gA1,
                                                __half* __restrict__ gU2s) {
  __shared__ __align__(16) _Float16 As[128 * AW];
  const int t = threadIdx.x;
  const int n0 = blockIdx.x * 128;
  {
    int i = t >> 1, q = t & 1;
    int row = n0 + i;
    _Float16* dst = As + i * AW + q * 64;
    if (row < NN) {
      const float* src = x + (size_t)row * 128 + q * 64;
#pragma unroll
      for (int c = 0; c < 64; c += 4) {
        float4 v = *reinterpret_cast<const float4*>(src + c);
        ushort4 u;
        u.x = __half_as_ushort(__float2half_rn(v.x));
        u.y = __half_as_ushort(__float2half_rn(v.y));
        u.z = __half_as_ushort(__float2half_rn(v.z));
        u.w = __half_as_ushort(__float2half_rn(v.w));
        *reinterpret_cast<ushort4*>(dst + c) = u;
      }
    } else {
#pragma unroll
      for (int c = 0; c < 64; c += 4)
        *reinterpret_cast<ushort4*>(dst + c) = make_ushort4(0, 0, 0, 0);
    }
  }
  __syncthreads();
  const int w = t >> 6, lane = t & 63;
  const int quad = lane >> 4, l = lane & 15;
  f4v acc[2][12];
#pragma unroll
  for (int mt = 0; mt < 2; ++mt)
#pragma unroll
    for (int nt = 0; nt < 12; ++nt) acc[mt][nt] = (f4v){0.f, 0.f, 0.f, 0.f};

#pragma unroll
  for (int ks = 0; ks < 4; ++ks) {
    int k0 = ks * 32 + quad * 8;
    h8 a0 = *reinterpret_cast<const h8*>(As + (w * 32 + l) * AW + k0);
    h8 a1 = *reinterpret_cast<const h8*>(As + (w * 32 + 16 + l) * AW + k0);
#pragma unroll
    for (int nt = 0; nt < 12; ++nt) {
      h8 b = *reinterpret_cast<const h8*>(BtX + (size_t)(nt * 16 + l) * 128 + k0);
      acc[0][nt] = __builtin_amdgcn_mfma_f32_16x16x32_f16(a0, b, acc[0][nt], 0, 0, 0);
      acc[1][nt] = __builtin_amdgcn_mfma_f32_16x16x32_f16(a1, b, acc[1][nt], 0, 0, 0);
    }
  }
#pragma unroll
  for (int mt = 0; mt < 2; ++mt) {
#pragma unroll
    for (int r = 0; r < 4; ++r) {
      int row = n0 + w * 32 + mt * 16 + quad * 4 + r;
      if (row < NN) {
        float dv = dinv[row];
#pragma unroll
        for (int nt2 = 0; nt2 < 4; ++nt2) {
          int col = nt2 * 16 + l;
          gV0[(size_t)row * 64 + col] = __float2half_rn(acc[mt][nt2][r]);
          gA1[(size_t)row * 64 + col] = __float2half_rn(acc[mt][4 + nt2][r]);
          gU2s[(size_t)row * 64 + col] = __float2half_rn(dv * acc[mt][8 + nt2][r]);
        }
      }
    }
  }
}

// ---------------------------------------------------------------------------
// MFMA GEMM H: [128 nodes] x [K=64] x [N=192] on h1.
static constexpr int HW2 = 72;  // LDS row stride (halves)
__global__ __launch_bounds__(256) void k_gemm_h(const __half* __restrict__ gH1,
                                                const __half* __restrict__ BtH2,
                                                const float* __restrict__ dinv,
                                                __half* __restrict__ gV02,
                                                __half* __restrict__ gA2,
                                                __half* __restrict__ gB2s) {
  __shared__ __align__(16) _Float16 As[128 * HW2];
  const int t = threadIdx.x;
  const int n0 = blockIdx.x * 128;
  for (int c = t; c < 128 * 8; c += 256) {
    int row = c >> 3, seg = c & 7;
    int rowg = n0 + row;
    h8 v = (h8){0, 0, 0, 0, 0, 0, 0, 0};
    if (rowg < NN) v = *reinterpret_cast<const h8*>(gH1 + (size_t)rowg * 64 + seg * 8);
    *reinterpret_cast<h8*>(As + row * HW2 + seg * 8) = v;
  }
  __syncthreads();
  const int w = t >> 6, lane = t & 63;
  const int quad = lane >> 4, l = lane & 15;
  f4v acc[2][12];
#pragma unroll
  for (int mt = 0; mt < 2; ++mt)
#pragma unroll
    for (int nt = 0; nt < 12; ++nt) acc[mt][nt] = (f4v){0.f, 0.f, 0.f, 0.f};
#pragma unroll
  for (int ks = 0; ks < 2; ++ks) {
    int k0 = ks * 32 + quad * 8;
    h8 a0 = *reinterpret_cast<const h8*>(As + (w * 32 + l) * HW2 + k0);
    h8 a1 = *reinterpret_cast<const h8*>(As + (w * 32 + 16 + l) * HW2 + k0);
#pragma unroll
    for (int nt = 0; nt < 12; ++nt) {
      h8 b = *reinterpret_cast<const h8*>(BtH2 + (size_t)(nt * 16 + l) * 64 + k0);
      acc[0][nt] = __builtin_amdgcn_mfma_f32_16x16x32_f16(a0, b, acc[0][nt], 0, 0, 0);
      acc[1][nt] = __builtin_amdgcn_mfma_f32_16x16x32_f16(a1, b, acc[1][nt], 0, 0, 0);
    }
  }
#pragma unroll
  for (int mt = 0; mt < 2; ++mt) {
#pragma unroll
    for (int r = 0; r < 4; ++r) {
      int row = n0 + w * 32 + mt * 16 + quad * 4 + r;
      if (row < NN) {
        float dv = dinv[row];
#pragma unroll
        for (int nt2 = 0; nt2 < 4; ++nt2) {
          int col = nt2 * 16 + l;
          gV02[(size_t)row * 64 + col] = __float2half_rn(acc[mt][nt2][r]);
          gA2[(size_t)row * 64 + col] = __float2half_rn(acc[mt][4 + nt2][r]);
          gB2s[(size_t)row * 64 + col] = __float2half_rn(dv * acc[mt][8 + nt2][r]);
        }
      }
    }
  }
}

// ---------------------------------------------------------------------------
// Gather core (r1 form — best measured): wave per node; each half-wave (32
// lanes) takes half of the node's edge list; lane covers 2 dims via __half2
// (32 lanes x 4B = one 128B row). adj holds pre-scaled byte offsets -> per-load
// address is one 32-bit add on a uniform base. Cross-half reduce at the end.
// NOTE (r1-r3 post-mortem): the prop kernels are pinned at FETCH/dur ~2.0TB/s
// regardless of inner-loop codegen (VALU halved, loads pinned: no change).
// They are at a memory-system wall for random 128B line misses; leave as-is.
__device__ __forceinline__ __half2 ld2(const char* tb, unsigned off) {
  return *reinterpret_cast<const __half2*>(tb + off);
}
__device__ __forceinline__ void acc2(float2& a, __half2 v) {
  float2 f = __half22float2(v);
  a.x += f.x;
  a.y += f.y;
}

#define GATHER_SUM2(TBL)                                                      \
  const char* tb = reinterpret_cast<const char*>(TBL);                        \
  int q0 = rp[node], q1 = rp[node + 1];                                       \
  int pm = q0 + ((q1 - q0 + 1) >> 1);                                         \
  int p = half ? pm : q0;                                                     \
  int p1 = half ? q1 : pm;                                                    \
  float2 A0 = make_float2(0.f, 0.f), A1 = A0, A2 = A0, A3 = A0;               \
  float2 A4 = A0, A5 = A0, A6 = A0, A7 = A0;                                  \
  int pA = (p + 3) & ~3;                                                      \
  if (pA > p1) pA = p1;                                                       \
  for (; p < pA; ++p) acc2(A0, ld2(tb, (unsigned)adj[p] + d4));               \
  for (; p + 16 <= p1; p += 16) {                                             \
    int4 e0 = *reinterpret_cast<const int4*>(adj + p);                        \
    int4 e1 = *reinterpret_cast<const int4*>(adj + p + 4);                    \
    int4 e2 = *reinterpret_cast<const int4*>(adj + p + 8);                    \
    int4 e3 = *reinterpret_cast<const int4*>(adj + p + 12);                   \
    __half2 v0 = ld2(tb, (unsigned)e0.x + d4);                                \
    __half2 v1 = ld2(tb, (unsigned)e0.y + d4);                                \
    __half2 v2 = ld2(tb, (unsigned)e0.z + d4);                                \
    __half2 v3 = ld2(tb, (unsigned)e0.w + d4);                                \
    __half2 v4 = ld2(tb, (unsigned)e1.x + d4);                                \
    __half2 v5 = ld2(tb, (unsigned)e1.y + d4);                                \
    __half2 v6 = ld2(tb, (unsigned)e1.z + d4);                                \
    __half2 v7 = ld2(tb, (unsigned)e1.w + d4);                                \
    __half2 v8 = ld2(tb, (unsigned)e2.x + d4);                                \
    __half2 v9 = ld2(tb, (unsigned)e2.y + d4);                                \
    __half2 va = ld2(tb, (unsigned)e2.z + d4);                                \
    __half2 vb = ld2(tb, (unsigned)e2.w + d4);                                \
    __half2 vc = ld2(tb, (unsigned)e3.x + d4);                                \
    __half2 vd = ld2(tb, (unsigned)e3.y + d4);                                \
    __half2 ve = ld2(tb, (unsigned)e3.z + d4);                                \
    __half2 vf = ld2(tb, (unsigned)e3.w + d4);                                \
    acc2(A0, v0); acc2(A1, v1); acc2(A2, v2); acc2(A3, v3);                   \
    acc2(A4, v4); acc2(A5, v5); acc2(A6, v6); acc2(A7, v7);                   \
    acc2(A0, v8); acc2(A1, v9); acc2(A2, va); acc2(A3, vb);                   \
    acc2(A4, vc); acc2(A5, vd); acc2(A6, ve); acc2(A7, vf);                   \
  }                                                                           \
  if (p + 8 <= p1) {                                                          \
    int4 e0 = *reinterpret_cast<const int4*>(adj + p);                        \
    int4 e1 = *reinterpret_cast<const int4*>(adj + p + 4);                    \
    acc2(A0, ld2(tb, (unsigned)e0.x + d4));                                   \
    acc2(A1, ld2(tb, (unsigned)e0.y + d4));                                   \
    acc2(A2, ld2(tb, (unsigned)e0.z + d4));                                   \
    acc2(A3, ld2(tb, (unsigned)e0.w + d4));                                   \
    acc2(A4, ld2(tb, (unsigned)e1.x + d4));                                   \
    acc2(A5, ld2(tb, (unsigned)e1.y + d4));                                   \
    acc2(A6, ld2(tb, (unsigned)e1.z + d4));                                   \
    acc2(A7, ld2(tb, (unsigned)e1.w + d4));                                   \
    p += 8;                                                                   \
  }                                                                           \
  if (p + 4 <= p1) {                                                          \
    int4 e = *reinterpret_cast<const int4*>(adj + p);                         \
    acc2(A0, ld2(tb, (unsigned)e.x + d4));                                    \
    acc2(A1, ld2(tb, (unsigned)e.y + d4));                                    \
    acc2(A2, ld2(tb, (unsigned)e.z + d4));                                    \
    acc2(A3, ld2(tb, (unsigned)e.w + d4));                                    \
    p += 4;                                                                   \
  }                                                                           \
  for (; p < p1; ++p) acc2(A1, ld2(tb, (unsigned)adj[p] + d4));               \
  float2 S;                                                                   \
  S.x = ((A0.x + A1.x) + (A2.x + A3.x)) + ((A4.x + A5.x) + (A6.x + A7.x));    \
  S.y = ((A0.y + A1.y) + (A2.y + A3.y)) + ((A4.y + A5.y) + (A6.y + A7.y));    \
  S.x += __shfl_xor(S.x, 32);                                                 \
  S.y += __shfl_xor(S.y, 32);

// prop A/C: t = -dv*sum(tbl); out = fp16(dv*(aux + 2t))
__global__ __launch_bounds__(256, 6) void k_propA(const int* __restrict__ rp,
                                                  const int* __restrict__ adj,
                                                  const __half* __restrict__ tbl,
                                                  const __half* __restrict__ aux,
                                                  const float* __restrict__ dinv,
                                                  __half* __restrict__ outT) {
  int t = threadIdx.x;
  int node = blockIdx.x * 4 + (t >> 6);
  int half = (t >> 5) & 1;
  int l = t & 31;
  unsigned d4 = (unsigned)l * 4;
  int d2 = l * 2;
  if (node >= NN) return;
  GATHER_SUM2(tbl)
  if (half == 0) {
    float dv = dinv[node];
    float tx = -dv * S.x, ty = -dv * S.y;
    size_t idx = (size_t)node * 64 + d2;
    float2 af = __half22float2(*reinterpret_cast<const __half2*>(aux + idx));
    *reinterpret_cast<__half2*>(outT + idx) =
        __floats2half2_rn(dv * (af.x + 2.f * tx), dv * (af.y + 2.f * ty));
  }
}

// prop B: r = -dv*sum(tbl); h1 = relu(V0 + r + b1)
__global__ __launch_bounds__(256, 6) void k_propB(const int* __restrict__ rp,
                                                  const int* __restrict__ adj,
                                                  const __half* __restrict__ tbl,
                                                  const __half* __restrict__ gV0,
                                                  const float* __restrict__ b1v,
                                                  const float* __restrict__ dinv,
                                                  __half* __restrict__ gH1) {
  int t = threadIdx.x;
  int node = blockIdx.x * 4 + (t >> 6);
  int half = (t >> 5) & 1;
  int l = t & 31;
  unsigned d4 = (unsigned)l * 4;
  int d2 = l * 2;
  if (node >= NN) return;
  GATHER_SUM2(tbl)
  if (half == 0) {
    float dv = dinv[node];
    float rx = -dv * S.x, ry = -dv * S.y;
    size_t idx = (size_t)node * 64 + d2;
    float2 vf0 = __half22float2(*reinterpret_cast<const __half2*>(gV0 + idx));
    float2 bb = *reinterpret_cast<const float2*>(b1v + d2);
    *reinterpret_cast<__half2*>(gH1 + idx) =
        __floats2half2_rn(fmaxf(vf0.x + rx + bb.x, 0.f),
                          fmaxf(vf0.y + ry + bb.y, 0.f));
  }
}

// prop D: r = -dv*sum(tbl); h2 = relu(V02 + r + b2) -> fp16 table (no atomics).
__global__ __launch_bounds__(256, 6) void k_propD(const int* __restrict__ rp,
                                                  const int* __restrict__ adj,
                                                  const __half* __restrict__ tbl,
                                                  const __half* __restrict__ gV02,
                                                  const float* __restrict__ b2v,
                                                  const float* __restrict__ dinv,
                                                  __half* __restrict__ gH2) {
  int t = threadIdx.x;
  int node = blockIdx.x * 4 + (t >> 6);
  int half = (t >> 5) & 1;
  int l = t & 31;
  unsigned d4 = (unsigned)l * 4;
  int d2 = l * 2;
  if (node >= NN) return;
  GATHER_SUM2(tbl)
  if (half == 0) {
    float dv = dinv[node];
    float rx = -dv * S.x, ry = -dv * S.y;
    size_t idx = (size_t)node * 64 + d2;
    float2 vf0 = __half22float2(*reinterpret_cast<const __half2*>(gV02 + idx));
    float2 bb = *reinterpret_cast<const float2*>(b2v + d2);
    *reinterpret_cast<__half2*>(gH2 + idx) =
        __floats2half2_rn(fmaxf(vf0.x + rx + bb.x, 0.f),
                          fmaxf(vf0.y + ry + bb.y, 0.f));
  }
}

// Pool: batch sorted -> run-length reduce 32 rows per wave, ~2 atomics each.
__global__ __launch_bounds__(256) void k_pool(const __half* __restrict__ gH2,
                                              const int* __restrict__ b32,
                                              float* __restrict__ pooled) {
  __shared__ int gb[128];
  int t = threadIdx.x;
  int n0 = blockIdx.x * 128;
  if (t < 128) gb[t] = (n0 + t < NN) ? b32[n0 + t] : -1;
  __syncthreads();
  int rg = t >> 6, d = t & 63;
  int base = rg * 32;
  int cur = -2;
  float s = 0.f;
  for (int i = 0; i < 32; ++i) {
    int g = gb[base + i];  // wave-uniform
    float v = (g >= 0) ? h2f(gH2[(size_t)(n0 + base + i) * 64 + d]) : 0.f;
    if (g != cur) {
      if (cur >= 0) atomAddF(&pooled[cur * 64 + d], s);
      s = 0.f;
      cur = g;
    }
    s += v;
  }
  if (cur >= 0) atomAddF(&pooled[cur * 64 + d], s);
}

// Final: out[g] = dot(pooled[g]/max(cnt,1), Wfc) + bfc
__global__ void k_out(const float* __restrict__ pooled, const int* __restrict__ gcnt,
                      const float* __restrict__ Wfc, const float* __restrict__ bfc,
                      float* __restrict__ out) {
  int g = blockIdx.x, t = threadIdx.x;  // 64 threads
  float v = pooled[g * 64 + t] * Wfc[t];
  int c = gcnt[g];
  v /= (float)(c > 0 ? c : 1);
  for (int off = 32; off > 0; off >>= 1) v += __shfl_down(v, off, 64);
  if (t == 0) out[g] = v + bfc[0];
}

// ---------------------------------------------------------------------------
extern "C" void kernel_launch(void* const* d_in, const int* in_sizes, int n_in,
                              void* d_out, int out_size, void* d_ws, size_t ws_size,
                              hipStream_t stream) {
  const float* x   = (const float*)d_in[0];
  const void*  ei  = d_in[1];
  const void*  bat = d_in[2];
  const float* W1  = (const float*)d_in[3];
  const float* b1v = (const float*)d_in[4];
  const float* W2  = (const float*)d_in[5];
  const float* b2v = (const float*)d_in[6];
  const float* Wfc = (const float*)d_in[7];
  const float* bfc = (const float*)d_in[8];
  float* out = (float*)d_out;

  char* w = (char*)d_ws;
  size_t o = 0;
  auto take = [&](size_t bytes) -> void* {
    void* p = w + o;
    o = (o + bytes + 255) & ~(size_t)255;
    return p;
  };
  int*      flag   = (int*)take(256);
  // ---- zero region start
  int*      gcnt   = (int*)take((size_t)NG * 4);
  float*    pooled = (float*)take((size_t)NG * 64 * 4);
  int*      dCnt   = (int*)take((size_t)(NBK + 2) * 4);
  int*      deg    = (int*)take((size_t)NN * 4);
  // ---- zero region end
  char*     zend   = w + o;
  int*      dBase  = (int*)take((size_t)(NBK + 2) * 4);
  int*      dCur   = (int*)take((size_t)(NBK + 2) * 4);
  int*      b32    = (int*)take((size_t)NN * 4);
  float*    dinv   = (float*)take((size_t)NN * 4);
  int*      rowptr = (int*)take((size_t)(NN + 2) * 4);
  int*      hdBlk  = (int*)take((size_t)256 * NBK * 4);
  unsigned* elist  = (unsigned*)take((size_t)NE * 4);
  int*      adj    = (int*)take((size_t)NE * 4);
  __half*   BtX    = (__half*)take((size_t)192 * 128 * 2);
  __half*   BtH2   = (__half*)take((size_t)192 * 64 * 2);
  __half*   gV0    = (__half*)take((size_t)NN * 64 * 2);
  __half*   gA1    = (__half*)take((size_t)NN * 64 * 2);
  __half*   gU2s   = (__half*)take((size_t)NN * 64 * 2);
  __half*   gM1    = (__half*)take((size_t)NN * 64 * 2);
  __half*   gH1    = (__half*)take((size_t)NN * 64 * 2);
  // aliases for layer 2 (source buffers dead by then):
  __half*   gV02   = gU2s;  // dead after propA(1)
  __half*   gA2    = gA1;   // dead after propA(1)
  __half*   gB2s   = gV0;   // dead after propB
  __half*   gM2    = gM1;   // dead after propB... consumed by propD
  __half*   gH2    = gH1;   // gH1 dead after gemm_h
  (void)in_sizes; (void)n_in; (void)out_size; (void)ws_size;

  hipMemsetAsync(gcnt, 0, (size_t)(zend - (char*)gcnt), stream);

  k_detect<<<1, 64, 0, stream>>>((const int*)ei, flag);
  k_front<<<GB_BATCH + GB_PREPW + GB_HIST, 256, 0, stream>>>(
      bat, ei, flag, W1, W2, b32, gcnt, BtX, BtH2, deg, dCnt, hdBlk);
  k_dinv<<<(NN + 255) / 256, 256, 0, stream>>>(deg, dinv);
  k_scan<<<1, 1024, 0, stream>>>(dCnt, dBase, dCur);
  k_scatter<<<256, 256, 0, stream>>>(ei, flag, hdBlk, dCur, elist);
  k_back<<<NBK, 256, 0, stream>>>(dBase, elist, rowptr, adj);

  const int gemm_grid = (NN + 127) / 128;  // 782
  const int prop_grid = (NN + 3) / 4;      // 25000

  // Layer 1: V0 | a1 | U2s, then lhat(a1 + 2*lhat(U2s)) via two 1-line rounds
  k_gemm_x<<<gemm_grid, 256, 0, stream>>>(x, BtX, dinv, gV0, gA1, gU2s);
  k_propA<<<prop_grid, 256, 0, stream>>>(rowptr, adj, gU2s, gA1, dinv, gM1);
  k_propB<<<prop_grid, 256, 0, stream>>>(rowptr, adj, gM1, gV0, b1v, dinv, gH1);
  // Layer 2: V02 | a2 | b2s, then two 1-line rounds; h2 table + separate pool
  k_gemm_h<<<gemm_grid, 256, 0, stream>>>(gH1, BtH2, dinv, gV02, gA2, gB2s);
  k_propA<<<prop_grid, 256, 0, stream>>>(rowptr, adj, gB2s, gA2, dinv, gM2);
  k_propD<<<prop_grid, 256, 0, stream>>>(rowptr, adj, gM2, gV02, b2v, dinv, gH2);
  k_pool<<<NBK, 256, 0, stream>>>(gH2, b32, pooled);
  k_out<<<NG, 64, 0, stream>>>(pooled, gcnt, Wfc, bfc, out);
}

// Round 5
// 608.173 us; speedup vs baseline: 1.1316x; 1.1316x over previous
//
#include <hip/hip_runtime.h>
#include <hip/hip_fp16.h>
#include <cstdint>
#include <cstddef>

// Problem constants (fixed by the reference)
static constexpr int NN = 100000;   // nodes
static constexpr int NE = 3200000;  // edges
static constexpr int NG = 256;      // graphs
static constexpr int NBK = (NN + 127) / 128;  // dst/src buckets of 128 nodes = 782
static constexpr int EPB = NE / 256;          // edges per hist/scatter block = 12500
static constexpr int GB_BATCH = (NN + 255) / 256;                    // 391
static constexpr int GB_PREPW = (192 * 128 + 192 * 64 + 255) / 256;  // 144

typedef _Float16 h8 __attribute__((ext_vector_type(8)));
typedef float f4v __attribute__((ext_vector_type(4)));

__device__ __forceinline__ void atomAddF(float* p, float v) {
  unsafeAtomicAdd(p, v);  // native global_atomic_add_f32 on gfx950
}
__device__ __forceinline__ float h2f(__half h) { return __half2float(h); }

// dtype hedge: reference says int64, harness doc says int32. Inline detect
// (64 uniform loads per block; removes the k_detect launch + flag round-trip).
__device__ __forceinline__ int detect_i64(const int* __restrict__ ei) {
  int nz = 0;
#pragma unroll
  for (int i = 0; i < 64; ++i) nz += (ei[2 * i + 1] != 0) ? 1 : 0;
  return (nz == 0) ? 1 : 0;  // 1 => int64 layout
}

__device__ __forceinline__ int ld_idx(const void* raw, int f, int i) {
  return f ? (int)((const long long*)raw)[i] : ((const int*)raw)[i];
}

// ---------------------------------------------------------------------------
// Front kernel: blockIdx ranges -> [batch repack+gcnt | weight prep]
__global__ __launch_bounds__(256) void k_front(const void* __restrict__ bat,
                                               const void* __restrict__ ei,
                                               const float* __restrict__ W1,
                                               const float* __restrict__ W2,
                                               int* __restrict__ b32,
                                               int* __restrict__ gcnt,
                                               __half* __restrict__ BtX,
                                               __half* __restrict__ BtH2) {
  __shared__ int cnt[256];
  int b = blockIdx.x;
  int t = threadIdx.x;
  if (b < GB_BATCH) {
    cnt[t] = 0;
    int blk0 = b * 256;
    int f = detect_i64((const int*)ei);
    int g0 = ld_idx(bat, f, blk0);
    __syncthreads();
    int i = blk0 + t;
    if (i < NN) {
      int g = ld_idx(bat, f, i);
      b32[i] = g;
      atomicAdd(&cnt[g - g0], 1);
    }
    __syncthreads();
    if (cnt[t] > 0) atomicAdd(&gcnt[g0 + t], cnt[t]);
  } else {
    // BtX[192][128]: rows 0-63=(W1_0-W1_2)^T, 64-127=W1_1^T, 128-191=W1_2^T
    // BtH2[192][64]: rows 0-63=(W2_0-W2_2)^T, 64-127=W2_1^T, 128-191=W2_2^T
    int u = (b - GB_BATCH) * 256 + t;
    if (u < 192 * 128) {
      int n = u >> 7, k = u & 127;
      float v;
      if (n < 64)       v = W1[k * 64 + n] - W1[16384 + k * 64 + n];
      else if (n < 128) v = W1[8192 + k * 64 + (n - 64)];
      else              v = W1[16384 + k * 64 + (n - 128)];
      BtX[n * 128 + k] = __float2half_rn(v);
    } else if (u < 192 * 128 + 192 * 64) {
      int u2 = u - 192 * 128;
      int n = u2 >> 6, k = u2 & 63;
      float v;
      if (n < 64)       v = W2[k * 64 + n] - W2[8192 + k * 64 + n];
      else if (n < 128) v = W2[4096 + k * 64 + (n - 64)];
      else              v = W2[8192 + k * 64 + (n - 128)];
      BtH2[n * 64 + k] = __float2half_rn(v);
    }
  }
}

// Edge histogram: 1024 threads/block (16 waves/CU vs 4 at 256t — this phase is
// latency-bound on LDS atomics + strided loads, r4 showed 10% occupancy).
__global__ __launch_bounds__(1024) void k_hist(const void* __restrict__ ei,
                                               int* __restrict__ sCnt,
                                               int* __restrict__ dCnt,
                                               int* __restrict__ hsBlk,
                                               int* __restrict__ hdBlk) {
  __shared__ int hs[NBK], hd[NBK];
  int t = threadIdx.x;
  int hb = blockIdx.x;
  for (int i = t; i < NBK; i += 1024) { hs[i] = 0; hd[i] = 0; }
  __syncthreads();
  int f = detect_i64((const int*)ei);
  int e0 = hb * EPB;
  for (int e = e0 + t; e < e0 + EPB; e += 1024) {
    int s = ld_idx(ei, f, e);
    int d = ld_idx(ei, f, NE + e);
    atomicAdd(&hs[s >> 7], 1);
    atomicAdd(&hd[d >> 7], 1);
  }
  __syncthreads();
  size_t hoff = (size_t)hb * NBK;
  for (int i = t; i < NBK; i += 1024) {
    int a = hs[i], c = hd[i];
    hsBlk[hoff + i] = a;
    hdBlk[hoff + i] = c;
    if (a) atomicAdd(&sCnt[i], a);
    if (c) atomicAdd(&dCnt[i], c);
  }
}

// Exclusive scan of both bucket-count arrays (782 <= 1024, one block).
__global__ __launch_bounds__(1024) void k_scan(const int* __restrict__ sCnt,
                                               const int* __restrict__ dCnt,
                                               int* __restrict__ sBase,
                                               int* __restrict__ dBase,
                                               int* __restrict__ sCur,
                                               int* __restrict__ dCur) {
  __shared__ int sh1[1024], sh2[1024];
  int t = threadIdx.x;
  int v1 = (t < NBK) ? sCnt[t] : 0;
  int v2 = (t < NBK) ? dCnt[t] : 0;
  sh1[t] = v1; sh2[t] = v2;
  __syncthreads();
  for (int off = 1; off < 1024; off <<= 1) {
    int a1 = (t >= off) ? sh1[t - off] : 0;
    int a2 = (t >= off) ? sh2[t - off] : 0;
    __syncthreads();
    sh1[t] += a1; sh2[t] += a2;
    __syncthreads();
  }
  if (t <= NBK) {
    int b1 = sh1[t] - v1, b2 = sh2[t] - v2;  // exclusive
    sBase[t] = b1; dBase[t] = b2;
    if (t < NBK) { sCur[t] = b1; dCur[t] = b2; }
  }
}

// Pass 2: chunk-reserve per (block,bucket) using saved per-block hists,
// scatter src ids (by src bucket) and packed (src | dst_local<<17) records.
// 1024 threads/block for TLP (same chunks, same placement semantics).
__global__ __launch_bounds__(1024) void k_scatter(const void* __restrict__ raw,
                                                  const int* __restrict__ hsBlk,
                                                  const int* __restrict__ hdBlk,
                                                  int* __restrict__ sCur,
                                                  int* __restrict__ dCur,
                                                  int* __restrict__ srclist,
                                                  unsigned* __restrict__ elist) {
  __shared__ int hs[NBK], hd[NBK], cbS[NBK], cbD[NBK];
  int t = threadIdx.x;
  size_t hb = (size_t)blockIdx.x * NBK;
  for (int i = t; i < NBK; i += 1024) {
    int c1 = hsBlk[hb + i];
    cbS[i] = c1 ? atomicAdd(&sCur[i], c1) : 0;
    int c2 = hdBlk[hb + i];
    cbD[i] = c2 ? atomicAdd(&dCur[i], c2) : 0;
    hs[i] = 0; hd[i] = 0;
  }
  __syncthreads();
  int f = detect_i64((const int*)raw);
  int e0 = blockIdx.x * EPB;
  for (int e = e0 + t; e < e0 + EPB; e += 1024) {
    int s = ld_idx(raw, f, e);
    int d = ld_idx(raw, f, NE + e);
    int bs = s >> 7, bd = d >> 7;
    int ls = atomicAdd(&hs[bs], 1);
    int ld2 = atomicAdd(&hd[bd], 1);
    srclist[cbS[bs] + ls] = s;
    elist[cbD[bd] + ld2] = (unsigned)s | ((unsigned)(d & 127) << 17);
  }
}

// Back kernel: [out-degree -> dinv | per-bucket counting sort -> CSR]
// adj entries are PRE-SCALED row byte offsets (node_id * 128) so the gather
// kernels need only one 32-bit add per load against a uniform base pointer.
__global__ __launch_bounds__(256) void k_back(const int* __restrict__ sBase,
                                              const int* __restrict__ srclist,
                                              float* __restrict__ dinv,
                                              const int* __restrict__ dBase,
                                              const unsigned* __restrict__ elist,
                                              int* __restrict__ rowptr,
                                              int* __restrict__ adj) {
  __shared__ int cnt[128], sc[128], off[128], fill[128];
  int t = threadIdx.x;
  int bb = blockIdx.x;
  if (bb < NBK) {
    int b = bb;
    if (t < 128) cnt[t] = 0;
    __syncthreads();
    int e0 = sBase[b], e1 = sBase[b + 1];
    for (int i = e0 + t; i < e1; i += 256) atomicAdd(&cnt[srclist[i] & 127], 1);
    __syncthreads();
    if (t < 128) {
      int node = b * 128 + t;
      if (node < NN) {
        int c = cnt[t];
        dinv[node] = (c > 0) ? rsqrtf((float)c) : 0.f;
      }
    }
  } else {
    int b = bb - NBK;
    if (t < 128) { cnt[t] = 0; fill[t] = 0; }
    __syncthreads();
    int e0 = dBase[b], e1 = dBase[b + 1];
    for (int i = e0 + t; i < e1; i += 256) atomicAdd(&cnt[elist[i] >> 17], 1);
    __syncthreads();
    if (t < 128) sc[t] = cnt[t];
    __syncthreads();
    for (int o = 1; o < 128; o <<= 1) {
      int a = (t < 128 && t >= o) ? sc[t - o] : 0;
      __syncthreads();
      if (t < 128) sc[t] += a;
      __syncthreads();
    }
    if (t < 128) {
      off[t] = sc[t] - cnt[t];  // exclusive
      int node = b * 128 + t;
      if (node < NN) rowptr[node] = e0 + off[t];
    }
    if (b == NBK - 1 && t == 0) rowptr[NN] = e1;
    __syncthreads();
    for (int i = e0 + t; i < e1; i += 256) {
      unsigned w2 = elist[i];
      int l = (int)(w2 >> 17);
      int pos = atomicAdd(&fill[l], 1);
      adj[e0 + off[l] + pos] = (int)((w2 & 0x1FFFFu) << 7);  // byte offset
    }
  }
}

// ---------------------------------------------------------------------------
// MFMA GEMM X: [128 nodes] x [K=128] x [N=192].
// Outputs (all fp16): gV0 = x@(W1_0-W1_2), gA1 = x@W1_1, gU2s = dinv.*(x@W1_2).
static constexpr int AW = 136;  // LDS row stride (halves)
__global__ __launch_bounds__(256) void k_gemm_x(const float* __restrict__ x,
                                                const __half* __restrict__ BtX,
                                                const float* __restrict__ dinv,
                                                __half* __restrict__ gV0,
                                                __half* __restrict__ gA1,
                                                __half* __restrict__ gU2s) {
  __shared__ __align__(16) _Float16 As[128 * AW];
  const int t = threadIdx.x;
  const int n0 = blockIdx.x * 128;
  {
    int i = t >> 1, q = t & 1;
    int row = n0 + i;
    _Float16* dst = As + i * AW + q * 64;
    if (row < NN) {
      const float* src = x + (size_t)row * 128 + q * 64;
#pragma unroll
      for (int c = 0; c < 64; c += 4) {
        float4 v = *reinterpret_cast<const float4*>(src + c);
        ushort4 u;
        u.x = __half_as_ushort(__float2half_rn(v.x));
        u.y = __half_as_ushort(__float2half_rn(v.y));
        u.z = __half_as_ushort(__float2half_rn(v.z));
        u.w = __half_as_ushort(__float2half_rn(v.w));
        *reinterpret_cast<ushort4*>(dst + c) = u;
      }
    } else {
#pragma unroll
      for (int c = 0; c < 64; c += 4)
        *reinterpret_cast<ushort4*>(dst + c) = make_ushort4(0, 0, 0, 0);
    }
  }
  __syncthreads();
  const int w = t >> 6, lane = t & 63;
  const int quad = lane >> 4, l = lane & 15;
  f4v acc[2][12];
#pragma unroll
  for (int mt = 0; mt < 2; ++mt)
#pragma unroll
    for (int nt = 0; nt < 12; ++nt) acc[mt][nt] = (f4v){0.f, 0.f, 0.f, 0.f};

#pragma unroll
  for (int ks = 0; ks < 4; ++ks) {
    int k0 = ks * 32 + quad * 8;
    h8 a0 = *reinterpret_cast<const h8*>(As + (w * 32 + l) * AW + k0);
    h8 a1 = *reinterpret_cast<const h8*>(As + (w * 32 + 16 + l) * AW + k0);
#pragma unroll
    for (int nt = 0; nt < 12; ++nt) {
      h8 b = *reinterpret_cast<const h8*>(BtX + (size_t)(nt * 16 + l) * 128 + k0);
      acc[0][nt] = __builtin_amdgcn_mfma_f32_16x16x32_f16(a0, b, acc[0][nt], 0, 0, 0);
      acc[1][nt] = __builtin_amdgcn_mfma_f32_16x16x32_f16(a1, b, acc[1][nt], 0, 0, 0);
    }
  }
#pragma unroll
  for (int mt = 0; mt < 2; ++mt) {
#pragma unroll
    for (int r = 0; r < 4; ++r) {
      int row = n0 + w * 32 + mt * 16 + quad * 4 + r;
      if (row < NN) {
        float dv = dinv[row];
#pragma unroll
        for (int nt2 = 0; nt2 < 4; ++nt2) {
          int col = nt2 * 16 + l;
          gV0[(size_t)row * 64 + col] = __float2half_rn(acc[mt][nt2][r]);
          gA1[(size_t)row * 64 + col] = __float2half_rn(acc[mt][4 + nt2][r]);
          gU2s[(size_t)row * 64 + col] = __float2half_rn(dv * acc[mt][8 + nt2][r]);
        }
      }
    }
  }
}

// ---------------------------------------------------------------------------
// MFMA GEMM H: [128 nodes] x [K=64] x [N=192] on h1.
static constexpr int HW2 = 72;  // LDS row stride (halves)
__global__ __launch_bounds__(256) void k_gemm_h(const __half* __restrict__ gH1,
                                                const __half* __restrict__ BtH2,
                                                const float* __restrict__ dinv,
                                                __half* __restrict__ gV02,
                                                __half* __restrict__ gA2,
                                                __half* __restrict__ gB2s) {
  __shared__ __align__(16) _Float16 As[128 * HW2];
  const int t = threadIdx.x;
  const int n0 = blockIdx.x * 128;
  for (int c = t; c < 128 * 8; c += 256) {
    int row = c >> 3, seg = c & 7;
    int rowg = n0 + row;
    h8 v = (h8){0, 0, 0, 0, 0, 0, 0, 0};
    if (rowg < NN) v = *reinterpret_cast<const h8*>(gH1 + (size_t)rowg * 64 + seg * 8);
    *reinterpret_cast<h8*>(As + row * HW2 + seg * 8) = v;
  }
  __syncthreads();
  const int w = t >> 6, lane = t & 63;
  const int quad = lane >> 4, l = lane & 15;
  f4v acc[2][12];
#pragma unroll
  for (int mt = 0; mt < 2; ++mt)
#pragma unroll
    for (int nt = 0; nt < 12; ++nt) acc[mt][nt] = (f4v){0.f, 0.f, 0.f, 0.f};
#pragma unroll
  for (int ks = 0; ks < 2; ++ks) {
    int k0 = ks * 32 + quad * 8;
    h8 a0 = *reinterpret_cast<const h8*>(As + (w * 32 + l) * HW2 + k0);
    h8 a1 = *reinterpret_cast<const h8*>(As + (w * 32 + 16 + l) * HW2 + k0);
#pragma unroll
    for (int nt = 0; nt < 12; ++nt) {
      h8 b = *reinterpret_cast<const h8*>(BtH2 + (size_t)(nt * 16 + l) * 64 + k0);
      acc[0][nt] = __builtin_amdgcn_mfma_f32_16x16x32_f16(a0, b, acc[0][nt], 0, 0, 0);
      acc[1][nt] = __builtin_amdgcn_mfma_f32_16x16x32_f16(a1, b, acc[1][nt], 0, 0, 0);
    }
  }
#pragma unroll
  for (int mt = 0; mt < 2; ++mt) {
#pragma unroll
    for (int r = 0; r < 4; ++r) {
      int row = n0 + w * 32 + mt * 16 + quad * 4 + r;
      if (row < NN) {
        float dv = dinv[row];
#pragma unroll
        for (int nt2 = 0; nt2 < 4; ++nt2) {
          int col = nt2 * 16 + l;
          gV02[(size_t)row * 64 + col] = __float2half_rn(acc[mt][nt2][r]);
          gA2[(size_t)row * 64 + col] = __float2half_rn(acc[mt][4 + nt2][r]);
          gB2s[(size_t)row * 64 + col] = __float2half_rn(dv * acc[mt][8 + nt2][r]);
        }
      }
    }
  }
}

// ---------------------------------------------------------------------------
// Gather core (r1 form — best measured): wave per node; each half-wave (32
// lanes) takes half of the node's edge list; lane covers 2 dims via __half2
// (32 lanes x 4B = one 128B row). adj holds pre-scaled byte offsets -> per-load
// address is one 32-bit add on a uniform base. Cross-half reduce at the end.
// NOTE (r1-r3 post-mortem): the prop kernels are pinned at FETCH/dur ~2.0TB/s
// regardless of inner-loop codegen (VALU halved, loads pinned: no change).
// They are at a memory-system wall for random 128B line misses; leave as-is.
__device__ __forceinline__ __half2 ld2(const char* tb, unsigned off) {
  return *reinterpret_cast<const __half2*>(tb + off);
}
__device__ __forceinline__ void acc2(float2& a, __half2 v) {
  float2 f = __half22float2(v);
  a.x += f.x;
  a.y += f.y;
}

#define GATHER_SUM2(TBL)                                                      \
  const char* tb = reinterpret_cast<const char*>(TBL);                        \
  int q0 = rp[node], q1 = rp[node + 1];                                       \
  int pm = q0 + ((q1 - q0 + 1) >> 1);                                         \
  int p = half ? pm : q0;                                                     \
  int p1 = half ? q1 : pm;                                                    \
  float2 A0 = make_float2(0.f, 0.f), A1 = A0, A2 = A0, A3 = A0;               \
  float2 A4 = A0, A5 = A0, A6 = A0, A7 = A0;                                  \
  int pA = (p + 3) & ~3;                                                      \
  if (pA > p1) pA = p1;                                                       \
  for (; p < pA; ++p) acc2(A0, ld2(tb, (unsigned)adj[p] + d4));               \
  for (; p + 16 <= p1; p += 16) {                                             \
    int4 e0 = *reinterpret_cast<const int4*>(adj + p);                        \
    int4 e1 = *reinterpret_cast<const int4*>(adj + p + 4);                    \
    int4 e2 = *reinterpret_cast<const int4*>(adj + p + 8);                    \
    int4 e3 = *reinterpret_cast<const int4*>(adj + p + 12);                   \
    __half2 v0 = ld2(tb, (unsigned)e0.x + d4);                                \
    __half2 v1 = ld2(tb, (unsigned)e0.y + d4);                                \
    __half2 v2 = ld2(tb, (unsigned)e0.z + d4);                                \
    __half2 v3 = ld2(tb, (unsigned)e0.w + d4);                                \
    __half2 v4 = ld2(tb, (unsigned)e1.x + d4);                                \
    __half2 v5 = ld2(tb, (unsigned)e1.y + d4);                                \
    __half2 v6 = ld2(tb, (unsigned)e1.z + d4);                                \
    __half2 v7 = ld2(tb, (unsigned)e1.w + d4);                                \
    __half2 v8 = ld2(tb, (unsigned)e2.x + d4);                                \
    __half2 v9 = ld2(tb, (unsigned)e2.y + d4);                                \
    __half2 va = ld2(tb, (unsigned)e2.z + d4);                                \
    __half2 vb = ld2(tb, (unsigned)e2.w + d4);                                \
    __half2 vc = ld2(tb, (unsigned)e3.x + d4);                                \
    __half2 vd = ld2(tb, (unsigned)e3.y + d4);                                \
    __half2 ve = ld2(tb, (unsigned)e3.z + d4);                                \
    __half2 vf = ld2(tb, (unsigned)e3.w + d4);                                \
    acc2(A0, v0); acc2(A1, v1); acc2(A2, v2); acc2(A3, v3);                   \
    acc2(A4, v4); acc2(A5, v5); acc2(A6, v6); acc2(A7, v7);                   \
    acc2(A0, v8); acc2(A1, v9); acc2(A2, va); acc2(A3, vb);                   \
    acc2(A4, vc); acc2(A5, vd); acc2(A6, ve); acc2(A7, vf);                   \
  }                                                                           \
  if (p + 8 <= p1) {                                                          \
    int4 e0 = *reinterpret_cast<const int4*>(adj + p);                        \
    int4 e1 = *reinterpret_cast<const int4*>(adj + p + 4);                    \
    acc2(A0, ld2(tb, (unsigned)e0.x + d4));                                   \
    acc2(A1, ld2(tb, (unsigned)e0.y + d4));                                   \
    acc2(A2, ld2(tb, (unsigned)e0.z + d4));                                   \
    acc2(A3, ld2(tb, (unsigned)e0.w + d4));                                   \
    acc2(A4, ld2(tb, (unsigned)e1.x + d4));                                   \
    acc2(A5, ld2(tb, (unsigned)e1.y + d4));                                   \
    acc2(A6, ld2(tb, (unsigned)e1.z + d4));                                   \
    acc2(A7, ld2(tb, (unsigned)e1.w + d4));                                   \
    p += 8;                                                                   \
  }                                                                           \
  if (p + 4 <= p1) {                                                          \
    int4 e = *reinterpret_cast<const int4*>(adj + p);                         \
    acc2(A0, ld2(tb, (unsigned)e.x + d4));                                    \
    acc2(A1, ld2(tb, (unsigned)e.y + d4));                                    \
    acc2(A2, ld2(tb, (unsigned)e.z + d4));                                    \
    acc2(A3, ld2(tb, (unsigned)e.w + d4));                                    \
    p += 4;                                                                   \
  }                                                                           \
  for (; p < p1; ++p) acc2(A1, ld2(tb, (unsigned)adj[p] + d4));               \
  float2 S;                                                                   \
  S.x = ((A0.x + A1.x) + (A2.x + A3.x)) + ((A4.x + A5.x) + (A6.x + A7.x));    \
  S.y = ((A0.y + A1.y) + (A2.y + A3.y)) + ((A4.y + A5.y) + (A6.y + A7.y));    \
  S.x += __shfl_xor(S.x, 32);                                                 \
  S.y += __shfl_xor(S.y, 32);

// prop A/C: t = -dv*sum(tbl); out = fp16(dv*(aux + 2t))
__global__ __launch_bounds__(256, 6) void k_propA(const int* __restrict__ rp,
                                                  const int* __restrict__ adj,
                                                  const __half* __restrict__ tbl,
                                                  const __half* __restrict__ aux,
                                                  const float* __restrict__ dinv,
                                                  __half* __restrict__ outT) {
  int t = threadIdx.x;
  int node = blockIdx.x * 4 + (t >> 6);
  int half = (t >> 5) & 1;
  int l = t & 31;
  unsigned d4 = (unsigned)l * 4;
  int d2 = l * 2;
  if (node >= NN) return;
  GATHER_SUM2(tbl)
  if (half == 0) {
    float dv = dinv[node];
    float tx = -dv * S.x, ty = -dv * S.y;
    size_t idx = (size_t)node * 64 + d2;
    float2 af = __half22float2(*reinterpret_cast<const __half2*>(aux + idx));
    *reinterpret_cast<__half2*>(outT + idx) =
        __floats2half2_rn(dv * (af.x + 2.f * tx), dv * (af.y + 2.f * ty));
  }
}

// prop B: r = -dv*sum(tbl); h1 = relu(V0 + r + b1)
__global__ __launch_bounds__(256, 6) void k_propB(const int* __restrict__ rp,
                                                  const int* __restrict__ adj,
                                                  const __half* __restrict__ tbl,
                                                  const __half* __restrict__ gV0,
                                                  const float* __restrict__ b1v,
                                                  const float* __restrict__ dinv,
                                                  __half* __restrict__ gH1) {
  int t = threadIdx.x;
  int node = blockIdx.x * 4 + (t >> 6);
  int half = (t >> 5) & 1;
  int l = t & 31;
  unsigned d4 = (unsigned)l * 4;
  int d2 = l * 2;
  if (node >= NN) return;
  GATHER_SUM2(tbl)
  if (half == 0) {
    float dv = dinv[node];
    float rx = -dv * S.x, ry = -dv * S.y;
    size_t idx = (size_t)node * 64 + d2;
    float2 vf0 = __half22float2(*reinterpret_cast<const __half2*>(gV0 + idx));
    float2 bb = *reinterpret_cast<const float2*>(b1v + d2);
    *reinterpret_cast<__half2*>(gH1 + idx) =
        __floats2half2_rn(fmaxf(vf0.x + rx + bb.x, 0.f),
                          fmaxf(vf0.y + ry + bb.y, 0.f));
  }
}

// prop D: r = -dv*sum(tbl); h2 = relu(V02 + r + b2) -> fp16 table (no atomics).
__global__ __launch_bounds__(256, 6) void k_propD(const int* __restrict__ rp,
                                                  const int* __restrict__ adj,
                                                  const __half* __restrict__ tbl,
                                                  const __half* __restrict__ gV02,
                                                  const float* __restrict__ b2v,
                                                  const float* __restrict__ dinv,
                                                  __half* __restrict__ gH2) {
  int t = threadIdx.x;
  int node = blockIdx.x * 4 + (t >> 6);
  int half = (t >> 5) & 1;
  int l = t & 31;
  unsigned d4 = (unsigned)l * 4;
  int d2 = l * 2;
  if (node >= NN) return;
  GATHER_SUM2(tbl)
  if (half == 0) {
    float dv = dinv[node];
    float rx = -dv * S.x, ry = -dv * S.y;
    size_t idx = (size_t)node * 64 + d2;
    float2 vf0 = __half22float2(*reinterpret_cast<const __half2*>(gV02 + idx));
    float2 bb = *reinterpret_cast<const float2*>(b2v + d2);
    *reinterpret_cast<__half2*>(gH2 + idx) =
        __floats2half2_rn(fmaxf(vf0.x + rx + bb.x, 0.f),
                          fmaxf(vf0.y + ry + bb.y, 0.f));
  }
}

// Pool: batch sorted -> run-length reduce 32 rows per wave, ~2 atomics each.
__global__ __launch_bounds__(256) void k_pool(const __half* __restrict__ gH2,
                                              const int* __restrict__ b32,
                                              float* __restrict__ pooled) {
  __shared__ int gb[128];
  int t = threadIdx.x;
  int n0 = blockIdx.x * 128;
  if (t < 128) gb[t] = (n0 + t < NN) ? b32[n0 + t] : -1;
  __syncthreads();
  int rg = t >> 6, d = t & 63;
  int base = rg * 32;
  int cur = -2;
  float s = 0.f;
  for (int i = 0; i < 32; ++i) {
    int g = gb[base + i];  // wave-uniform
    float v = (g >= 0) ? h2f(gH2[(size_t)(n0 + base + i) * 64 + d]) : 0.f;
    if (g != cur) {
      if (cur >= 0) atomAddF(&pooled[cur * 64 + d], s);
      s = 0.f;
      cur = g;
    }
    s += v;
  }
  if (cur >= 0) atomAddF(&pooled[cur * 64 + d], s);
}

// Final: out[g] = dot(pooled[g]/max(cnt,1), Wfc) + bfc
__global__ void k_out(const float* __restrict__ pooled, const int* __restrict__ gcnt,
                      const float* __restrict__ Wfc, const float* __restrict__ bfc,
                      float* __restrict__ out) {
  int g = blockIdx.x, t = threadIdx.x;  // 64 threads
  float v = pooled[g * 64 + t] * Wfc[t];
  int c = gcnt[g];
  v /= (float)(c > 0 ? c : 1);
  for (int off = 32; off > 0; off >>= 1) v += __shfl_down(v, off, 64);
  if (t == 0) out[g] = v + bfc[0];
}

// ---------------------------------------------------------------------------
extern "C" void kernel_launch(void* const* d_in, const int* in_sizes, int n_in,
                              void* d_out, int out_size, void* d_ws, size_t ws_size,
                              hipStream_t stream) {
  const float* x   = (const float*)d_in[0];
  const void*  ei  = d_in[1];
  const void*  bat = d_in[2];
  const float* W1  = (const float*)d_in[3];
  const float* b1v = (const float*)d_in[4];
  const float* W2  = (const float*)d_in[5];
  const float* b2v = (const float*)d_in[6];
  const float* Wfc = (const float*)d_in[7];
  const float* bfc = (const float*)d_in[8];
  float* out = (float*)d_out;

  char* w = (char*)d_ws;
  size_t o = 0;
  auto take = [&](size_t bytes) -> void* {
    void* p = w + o;
    o = (o + bytes + 255) & ~(size_t)255;
    return p;
  };
  // ---- zero region start
  int*      gcnt   = (int*)take((size_t)NG * 4);
  float*    pooled = (float*)take((size_t)NG * 64 * 4);
  int*      sCnt   = (int*)take((size_t)(NBK + 2) * 4);
  int*      dCnt   = (int*)take((size_t)(NBK + 2) * 4);
  // ---- zero region end
  char*     zend   = w + o;
  int*      sBase  = (int*)take((size_t)(NBK + 2) * 4);
  int*      dBase  = (int*)take((size_t)(NBK + 2) * 4);
  int*      sCur   = (int*)take((size_t)(NBK + 2) * 4);
  int*      dCur   = (int*)take((size_t)(NBK + 2) * 4);
  int*      b32    = (int*)take((size_t)NN * 4);
  float*    dinv   = (float*)take((size_t)NN * 4);
  int*      rowptr = (int*)take((size_t)(NN + 2) * 4);
  int*      hsBlk  = (int*)take((size_t)256 * NBK * 4);
  int*      hdBlk  = (int*)take((size_t)256 * NBK * 4);
  int*      srclist= (int*)take((size_t)NE * 4);
  unsigned* elist  = (unsigned*)take((size_t)NE * 4);
  int*      adj    = (int*)take((size_t)NE * 4);
  __half*   BtX    = (__half*)take((size_t)192 * 128 * 2);
  __half*   BtH2   = (__half*)take((size_t)192 * 64 * 2);
  __half*   gV0    = (__half*)take((size_t)NN * 64 * 2);
  __half*   gA1    = (__half*)take((size_t)NN * 64 * 2);
  __half*   gU2s   = (__half*)take((size_t)NN * 64 * 2);
  __half*   gM1    = (__half*)take((size_t)NN * 64 * 2);
  __half*   gH1    = (__half*)take((size_t)NN * 64 * 2);
  // aliases for layer 2 (source buffers dead by then):
  __half*   gV02   = gU2s;  // dead after propA(1)
  __half*   gA2    = gA1;   // dead after propA(1)
  __half*   gB2s   = gV0;   // dead after propB
  __half*   gM2    = gM1;   // dead after propB... consumed by propD
  __half*   gH2    = gH1;   // gH1 dead after gemm_h
  (void)in_sizes; (void)n_in; (void)out_size; (void)ws_size;

  hipMemsetAsync(gcnt, 0, (size_t)(zend - (char*)gcnt), stream);

  k_front<<<GB_BATCH + GB_PREPW, 256, 0, stream>>>(bat, ei, W1, W2, b32, gcnt, BtX, BtH2);
  k_hist<<<256, 1024, 0, stream>>>(ei, sCnt, dCnt, hsBlk, hdBlk);
  k_scan<<<1, 1024, 0, stream>>>(sCnt, dCnt, sBase, dBase, sCur, dCur);
  k_scatter<<<256, 1024, 0, stream>>>(ei, hsBlk, hdBlk, sCur, dCur, srclist, elist);
  k_back<<<2 * NBK, 256, 0, stream>>>(sBase, srclist, dinv, dBase, elist, rowptr, adj);

  const int gemm_grid = (NN + 127) / 128;  // 782
  const int prop_grid = (NN + 3) / 4;      // 25000

  // Layer 1: V0 | a1 | U2s, then lhat(a1 + 2*lhat(U2s)) via two 1-line rounds
  k_gemm_x<<<gemm_grid, 256, 0, stream>>>(x, BtX, dinv, gV0, gA1, gU2s);
  k_propA<<<prop_grid, 256, 0, stream>>>(rowptr, adj, gU2s, gA1, dinv, gM1);
  k_propB<<<prop_grid, 256, 0, stream>>>(rowptr, adj, gM1, gV0, b1v, dinv, gH1);
  // Layer 2: V02 | a2 | b2s, then two 1-line rounds; h2 table + separate pool
  k_gemm_h<<<gemm_grid, 256, 0, stream>>>(gH1, BtH2, dinv, gV02, gA2, gB2s);
  k_propA<<<prop_grid, 256, 0, stream>>>(rowptr, adj, gB2s, gA2, dinv, gM2);
  k_propD<<<prop_grid, 256, 0, stream>>>(rowptr, adj, gM2, gV02, b2v, dinv, gH2);
  k_pool<<<NBK, 256, 0, stream>>>(gH2, b32, pooled);
  k_out<<<NG, 64, 0, stream>>>(pooled, gcnt, Wfc, bfc, out);
}